// Round 1
// 314.628 us; speedup vs baseline: 1.0011x; 1.0011x over previous
//
#include <hip/hip_runtime.h>
#include <stdint.h>

// RandomSaltPepper: out = where(mask, color, imgs)
//   imgs: (64, 3, 512, 512) f32
//   mask  = uniform(k1, (B,1,H,W)) < 0.5     -> per-(b,h,w), shared over C
//   idx   = randint(k2, (B,1,H,W), 0, 2); color = idx==0 ? 1.0 : 0.0
//   k1,k2 = split(key(42))
//
// JAX randint internally does ANOTHER split: k2a_, k2b_ = split(k2);
// for span=2 the multiplier is 0, so idx = random_bits(k2b_) & 1.
// (jax/_src/random.py::_randint — higher_bits*0 + lower_bits%2)
//
// Exact JAX Threefry-2x32 replication, partitionable (default >= 0.4.30).
//
// V2 (this round): 4 pixels/thread, float4 nontemporal loads/stores,
// 8 independent Threefry chains per thread for ILP. Traffic unchanged
// (403 MB); goal is to close the ~10% gap to the 6.3-6.5 TB/s fill-kernel
// ceiling on the kernel dispatch itself.
#define JAX_PARTITIONABLE 1

constexpr int B = 64, C = 3, H = 512, W = 512;
constexpr uint32_t HW   = (uint32_t)H * W;        // 262144
constexpr uint32_t NPIX = (uint32_t)B * HW;       // 16777216
constexpr uint32_t CHW  = (uint32_t)C * HW;       // 786432
constexpr uint32_t HW4  = HW / 4u;                // 65536  (float4 units)
constexpr uint32_t CHW4 = CHW / 4u;               // 196608 (float4 units)

typedef float f32x4 __attribute__((ext_vector_type(4)));

#define ROTL32(x, r) (((x) << (r)) | ((x) >> (32 - (r))))

__host__ __device__ __forceinline__ void tf2x32(uint32_t k0, uint32_t k1,
                                                uint32_t x0, uint32_t x1,
                                                uint32_t* o0, uint32_t* o1) {
  const uint32_t ks0 = k0, ks1 = k1, ks2 = k0 ^ k1 ^ 0x1BD11BDAu;
  x0 += ks0; x1 += ks1;
#define TF_R4(ra, rb, rc, rd)                      \
  x0 += x1; x1 = ROTL32(x1, ra); x1 ^= x0;         \
  x0 += x1; x1 = ROTL32(x1, rb); x1 ^= x0;         \
  x0 += x1; x1 = ROTL32(x1, rc); x1 ^= x0;         \
  x0 += x1; x1 = ROTL32(x1, rd); x1 ^= x0;
  TF_R4(13, 15, 26, 6);  x0 += ks1; x1 += ks2 + 1u;
  TF_R4(17, 29, 16, 24); x0 += ks2; x1 += ks0 + 2u;
  TF_R4(13, 15, 26, 6);  x0 += ks0; x1 += ks1 + 3u;
  TF_R4(17, 29, 16, 24); x0 += ks1; x1 += ks2 + 4u;
  TF_R4(13, 15, 26, 6);  x0 += ks2; x1 += ks0 + 5u;
#undef TF_R4
  *o0 = x0; *o1 = x1;
}

#if JAX_PARTITIONABLE
// 32-bit random word at flat index j: fold both halves of threefry(key, 0, j)
__device__ __forceinline__ uint32_t rand_word(uint32_t ka, uint32_t kb, uint32_t j) {
  uint32_t o0, o1;
  tf2x32(ka, kb, 0u, j, &o0, &o1);
  return o0 ^ o1;
}
#else
// Legacy: counts iota(N) split into halves; pairs (j, j+N/2);
// word(j) = j < N/2 ? out0(j, j+N/2) : out1(j-N/2, j)
__device__ __forceinline__ uint32_t rand_word(uint32_t ka, uint32_t kb, uint32_t j) {
  constexpr uint32_t HALF = NPIX / 2;
  uint32_t o0, o1;
  if (j < HALF) {
    tf2x32(ka, kb, j, j + HALF, &o0, &o1);
    return o0;
  } else {
    tf2x32(ka, kb, j - HALF, j, &o0, &o1);
    return o1;
  }
}
#endif

__global__ __launch_bounds__(256) void RandomSaltPepper_9380208574641_kernel(
    const f32x4* __restrict__ in, f32x4* __restrict__ out,
    uint32_t mka, uint32_t mkb, uint32_t cka, uint32_t ckb) {
  // One thread owns 4 consecutive pixels (same b, consecutive hw) x 3 channels.
  const uint32_t t  = blockIdx.x * 256u + threadIdx.x;   // 0 .. NPIX/4-1
  const uint32_t j0 = t << 2;                            // first pixel index
  const uint32_t b  = j0 >> 18;                          // j0 / HW
  const uint32_t hw = j0 & (HW - 1u);                    // j0 % HW (multiple of 4)
  const uint32_t base = b * CHW4 + (hw >> 2);            // float4-unit index

  // Issue the 3 channel loads first so HBM latency hides under Threefry.
  const f32x4 v0 = __builtin_nontemporal_load(&in[base]);
  const f32x4 v1 = __builtin_nontemporal_load(&in[base + HW4]);
  const f32x4 v2 = __builtin_nontemporal_load(&in[base + 2u * HW4]);

  // 8 independent Threefry chains (mask + color for 4 pixels).
  uint32_t mb[4], cb[4];
#pragma unroll
  for (int i = 0; i < 4; ++i) {
    mb[i] = rand_word(mka, mkb, j0 + (uint32_t)i);
    cb[i] = rand_word(cka, ckb, j0 + (uint32_t)i);
  }

  float col[4];
  bool  msk[4];
#pragma unroll
  for (int i = 0; i < 4; ++i) {
    // mask: uniform < 0.5  <=>  MSB of random word == 0
    msk[i] = (mb[i] & 0x80000000u) == 0u;
    // color: lower_bits & 1 == 0 -> salt(1.0), else pepper(0.0)
    col[i] = (cb[i] & 1u) ? 0.0f : 1.0f;
  }

  f32x4 o0, o1, o2;
#pragma unroll
  for (int i = 0; i < 4; ++i) {
    o0[i] = msk[i] ? col[i] : v0[i];
    o1[i] = msk[i] ? col[i] : v1[i];
    o2[i] = msk[i] ? col[i] : v2[i];
  }

  __builtin_nontemporal_store(o0, &out[base]);
  __builtin_nontemporal_store(o1, &out[base + HW4]);
  __builtin_nontemporal_store(o2, &out[base + 2u * HW4]);
}

extern "C" void kernel_launch(void* const* d_in, const int* in_sizes, int n_in,
                              void* d_out, int out_size, void* d_ws, size_t ws_size,
                              hipStream_t stream) {
  const f32x4* imgs = (const f32x4*)d_in[0];
  f32x4* out = (f32x4*)d_out;

  // Host-side key derivation (deterministic, identical every call):
  //   k1, k2 = split(key(42)); color_key = split(k2)[1]
  const uint32_t pk0 = 0u, pk1 = 42u;
  uint32_t k1a, k1b, k2a, k2b, cka, ckb;
#if JAX_PARTITIONABLE
  // foldlike split: subkey i of split(key) = threefry(key, hi=0, lo=i)
  tf2x32(pk0, pk1, 0u, 0u, &k1a, &k1b);   // k1 (mask key)
  tf2x32(pk0, pk1, 0u, 1u, &k2a, &k2b);   // k2
  uint32_t t0, t1;
  tf2x32(k2a, k2b, 0u, 0u, &t0, &t1);     // split(k2)[0] (higher_bits, unused)
  tf2x32(k2a, k2b, 0u, 1u, &cka, &ckb);   // split(k2)[1] -> lower_bits key
  (void)t0; (void)t1;
#else
  // original split: counts [0,1,2,3] -> x0=[0,1], x1=[2,3];
  // keys = reshape(concat(o0,o1), (2,2)): k1=(o0(0,2),o0(1,3)), k2=(o1(0,2),o1(1,3))
  uint32_t a0, a1, b0, b1;
  tf2x32(pk0, pk1, 0u, 2u, &a0, &b0);
  tf2x32(pk0, pk1, 1u, 3u, &a1, &b1);
  k1a = a0; k1b = a1; k2a = b0; k2b = b1;
  // inner split(k2), same original scheme; lower_bits key = second row
  uint32_t c0, c1, d0, d1;
  tf2x32(k2a, k2b, 0u, 2u, &c0, &d0);
  tf2x32(k2a, k2b, 1u, 3u, &c1, &d1);
  cka = d0; ckb = d1;
#endif

  const int threads = 256;
  const int blocks = (int)(NPIX / 4u / (uint32_t)threads);  // 16384
  RandomSaltPepper_9380208574641_kernel<<<blocks, threads, 0, stream>>>(
      imgs, out, k1a, k1b, cka, ckb);
}